// Round 10
// baseline (139.791 us; speedup 1.0000x reference)
//
#include <hip/hip_runtime.h>
#include <hip/hip_bf16.h>

typedef _Float16 half8 __attribute__((ext_vector_type(8)));
typedef _Float16 half4v __attribute__((ext_vector_type(4)));
typedef __fp16 fp16x2 __attribute__((ext_vector_type(2)));   // cvt_pkrtz return type
typedef float floatx4 __attribute__((ext_vector_type(4)));

// Problem constants: B=8, N=1024, D=512, H=8, DH=64
#define BB 8
#define NN 1024
#define DD 512
#define HH 8
#define DHH 64
#define LOG2E 1.4426950408889634f

// hardware 2^x (v_exp_f32)
#define EXP2F(x) __builtin_amdgcn_exp2f(x)

// async global->LDS, 16B per lane, dest = wave-uniform base + lane*16
__device__ __forceinline__ void gload_lds16(const _Float16* g, _Float16* l) {
    __builtin_amdgcn_global_load_lds(
        (const __attribute__((address_space(1))) void*)g,
        (__attribute__((address_space(3))) void*)l, 16, 0, 0);
}

// ---------------- W fp32->fp16 transpose only ----------------
// 192 blocks: 3 matrices x 64 tiles of 64x64. Wq pre-scaled by log2(e).
__global__ __launch_bounds__(256) void cvt_kernel(const float* __restrict__ Wq,
                                                  const float* __restrict__ Wk,
                                                  const float* __restrict__ Wv,
                                                  _Float16* __restrict__ Wt) {
    __shared__ __align__(16) _Float16 tb[64][72];
    int t = blockIdx.x;                // 0..191
    int tid = threadIdx.x;
    int which = t >> 6;                // /64
    int rem = t & 63;
    int kt = (rem >> 3) * 64, nt = (rem & 7) * 64;
    const float* W = (which == 0) ? Wq : (which == 1) ? Wk : Wv;
    float wscale = (which == 0) ? LOG2E : 1.0f;
    _Float16* Wto = Wt + (size_t)which * DD * DD;
    for (int i = 0; i < 16; i++) {
        int idx = tid + i * 256;
        int r = idx >> 6, c = idx & 63;
        tb[c][r] = (_Float16)(W[(size_t)(kt + r) * DD + nt + c] * wscale);
    }
    __syncthreads();
    for (int i = 0; i < 16; i++) {
        int idx = tid + i * 256;
        int r = idx >> 6, c = idx & 63;
        Wto[(size_t)(nt + r) * DD + kt + c] = tb[r][c];
    }
}

// ---------------- QKV projection, 128x128 tile (unchanged from round 8) ----------------
__global__ __launch_bounds__(256) void qkv_gemm_kernel(const float* __restrict__ x,
                                                       const _Float16* __restrict__ Wt,
                                                       const float* __restrict__ bq,
                                                       const float* __restrict__ bk,
                                                       const float* __restrict__ bv,
                                                       _Float16* __restrict__ QKV) {
    __shared__ __align__(16) _Float16 Ws[128 * 32];   // W rows (features)
    __shared__ __align__(16) _Float16 Xs[128 * 32];   // x rows (tokens)

    int which = blockIdx.z;
    const _Float16* Wtw = Wt + (size_t)which * DD * DD;
    const float* bias = (which == 0) ? bq : (which == 1) ? bk : bv;
    const float bscale = (which == 0) ? LOG2E : 1.0f;

    int tid = threadIdx.x;
    int wave = tid >> 6, lane = tid & 63;
    int quad = lane >> 4, l16 = lane & 15;
    int wm = wave >> 1, wn = wave & 1;
    int mBase = blockIdx.x * 128;   // tokens  (token-major for XCD L2 reuse)
    int nBase = blockIdx.y * 128;   // features

    int srow = wave * 32 + (lane >> 2);
    int scol = (lane & 3) * 8;
    const _Float16* wg = Wtw + (size_t)(nBase + srow) * DD + scol;
    const float*    xg = x   + (size_t)(mBase + srow) * DD + scol;
    _Float16* wl = Ws + (wave * 32) * 32;

    floatx4 acc[4][4];
    for (int i = 0; i < 4; i++)
        for (int j = 0; j < 4; j++) acc[i][j] = (floatx4){0.f, 0.f, 0.f, 0.f};

    for (int kk = 0; kk < DD; kk += 32) {
        __syncthreads();
        gload_lds16(wg + kk,           wl);
        gload_lds16(wg + 16 * DD + kk, wl + 16 * 32);
        float4 a0 = *(const float4*)(xg + kk);
        float4 a1 = *(const float4*)(xg + kk + 4);
        float4 b0 = *(const float4*)(xg + 16 * DD + kk);
        float4 b1 = *(const float4*)(xg + 16 * DD + kk + 4);
        half8 ha, hb;
        ha[0] = (_Float16)a0.x; ha[1] = (_Float16)a0.y; ha[2] = (_Float16)a0.z; ha[3] = (_Float16)a0.w;
        ha[4] = (_Float16)a1.x; ha[5] = (_Float16)a1.y; ha[6] = (_Float16)a1.z; ha[7] = (_Float16)a1.w;
        hb[0] = (_Float16)b0.x; hb[1] = (_Float16)b0.y; hb[2] = (_Float16)b0.z; hb[3] = (_Float16)b0.w;
        hb[4] = (_Float16)b1.x; hb[5] = (_Float16)b1.y; hb[6] = (_Float16)b1.z; hb[7] = (_Float16)b1.w;
        *(half8*)&Xs[srow * 32 + scol] = ha;
        *(half8*)&Xs[(srow + 16) * 32 + scol] = hb;
        __syncthreads();

        half8 af[4], bf[4];
        if (which < 2) {
            for (int i = 0; i < 4; i++)
                af[i] = *(const half8*)&Ws[(wm * 64 + i * 16 + l16) * 32 + quad * 8];
            for (int j = 0; j < 4; j++)
                bf[j] = *(const half8*)&Xs[(wn * 64 + j * 16 + l16) * 32 + quad * 8];
        } else {
            for (int i = 0; i < 4; i++)
                af[i] = *(const half8*)&Xs[(wm * 64 + i * 16 + l16) * 32 + quad * 8];
            for (int j = 0; j < 4; j++)
                bf[j] = *(const half8*)&Ws[(wn * 64 + j * 16 + l16) * 32 + quad * 8];
        }
        for (int i = 0; i < 4; i++)
            for (int j = 0; j < 4; j++)
                acc[i][j] = __builtin_amdgcn_mfma_f32_16x16x32_f16(af[i], bf[j], acc[i][j], 0, 0, 0);
    }

    if (which < 2) {
        _Float16* out = QKV + (size_t)which * (BB * NN) * DD;
        for (int i = 0; i < 4; i++) {
            int feat0 = nBase + wm * 64 + i * 16 + quad * 4;
            float4 b4 = *(const float4*)&bias[feat0];
            b4.x *= bscale; b4.y *= bscale; b4.z *= bscale; b4.w *= bscale;
            for (int j = 0; j < 4; j++) {
                int token = mBase + wn * 64 + j * 16 + l16;
                half4v pack;
                pack[0] = (_Float16)(acc[i][j][0] + b4.x);
                pack[1] = (_Float16)(acc[i][j][1] + b4.y);
                pack[2] = (_Float16)(acc[i][j][2] + b4.z);
                pack[3] = (_Float16)(acc[i][j][3] + b4.w);
                *(half4v*)&out[(size_t)token * DD + feat0] = pack;
            }
        }
    } else {
        _Float16* VT = QKV + (size_t)2 * (BB * NN) * DD;
        for (int j = 0; j < 4; j++) {
            int col = nBase + wn * 64 + j * 16 + l16;
            float bval = bias[col];
            for (int i = 0; i < 4; i++) {
                int row0 = mBase + wm * 64 + i * 16 + quad * 4;
                int b = row0 >> 10;
                int n = row0 & 1023;
                half4v pack;
                for (int reg = 0; reg < 4; reg++) pack[reg] = (_Float16)(acc[i][j][reg] + bval);
                *(half4v*)&VT[((size_t)b * 512 + col) * 1024 + n] = pack;
            }
        }
    }
}

// per-wave K/V tile staging: 4x gload_lds16, pre-swizzled global src, linear LDS dest
__device__ __forceinline__ void stage_kv(const _Float16* kg, const _Float16* vg,
                                         _Float16* kl, _Float16* vl, int kt) {
    const _Float16* kgk = kg + (size_t)(kt * 64) * DD;
    const _Float16* vgk = vg + kt * 64;
    gload_lds16(kgk,            kl);
    gload_lds16(kgk + 8 * DD,   kl + 8 * 64);
    gload_lds16(vgk,            vl);
    gload_lds16(vgk + 8 * 1024, vl + 8 * 64);
}

// ---------------- flash attention, S^T formulation, Br=128 ----------------
// Round 10 (= round 9 + cvt_pkrtz type fix): 32 q-rows/wave (2 q-groups) —
// kf/vf LDS reads amortized over 2x the MFMAs (per-q LDS read traffic halved;
// attn is LDS+VALU issue-bound per round-0 counter decomposition). Hoisted LDS
// index bases + manual x2 unroll (compile-time cur) kill per-tile address VALU.
// cvt_pkrtz pack (2 ops vs 4). Exp-first softmax (exp2 domain), dbuf K/V,
// XCD-pinned mapping, s_setprio.
// grid 512 (2 blocks/CU), block 256 (4 waves). LDS 48KB.
__global__ __launch_bounds__(256) void attn_kernel(const _Float16* __restrict__ QKV,
                                                   float* __restrict__ out) {
    const _Float16* Q  = QKV;
    const _Float16* K  = QKV + (size_t)(BB * NN) * DD;
    const _Float16* VT = QKV + (size_t)2 * (BB * NN) * DD;

    __shared__ __align__(16) _Float16 Kt[2][64 * 64];      // [key][d], swizzled
    __shared__ __align__(16) _Float16 Vt[2][64 * 64];      // [d][key], swizzled
    __shared__ __align__(16) _Float16 PT[4][2][16 * 64];   // per-wave, per-group

    int tid = threadIdx.x;
    int wave = tid >> 6, lane = tid & 63;
    int quad = lane >> 4, l16 = lane & 15;
    int l16sw = l16 & 7;
    // XCD-pinned decode (512 blocks): bid&7 = batch b; h, qt within XCD.
    int bid = blockIdx.x;
    int b = bid & 7;
    int local = bid >> 3;      // 0..63
    int h = local & 7;
    int qt = local >> 3;       // 0..7

    const _Float16* Qb  = Q + ((size_t)b * NN) * DD + h * DHH;
    const _Float16* Kb  = K + ((size_t)b * NN) * DD + h * DHH;
    const _Float16* VTb = VT + ((size_t)b * 512 + h * 64) * 1024;

    // Q fragments: 2 groups x 2 k-splits
    int qrow0 = qt * 128 + wave * 32 + l16;
    half8 qf[2][2];
    for (int g = 0; g < 2; g++)
        for (int ks = 0; ks < 2; ks++)
            qf[g][ks] = *(const half8*)(Qb + (size_t)(qrow0 + g * 16) * DD + ks * 32 + quad * 8);

    floatx4 o[4][2];
    for (int nt = 0; nt < 4; nt++)
        for (int g = 0; g < 2; g++) o[nt][g] = (floatx4){0.f, 0.f, 0.f, 0.f};
    float m0 = 0.f, m1 = 0.f, l0 = 0.f, l1 = 0.f;   // exp-first: m init 0

    // staging (pre-swizzled global src, linear LDS dest)
    int srow = lane >> 3;
    int schunk = (lane & 7) ^ srow;
    const _Float16* kg = Kb + (size_t)(wave * 16 + srow) * DD + schunk * 8;
    const _Float16* vg = VTb + (size_t)(wave * 16 + srow) * 1024 + schunk * 8;
    _Float16* kl0 = &Kt[0][(wave * 16) * 64];
    _Float16* vl0 = &Vt[0][(wave * 16) * 64];
    _Float16* kl1 = &Kt[1][(wave * 16) * 64];
    _Float16* vl1 = &Vt[1][(wave * 16) * 64];

    // hoisted LDS index bases (elements). kf/vf/pf share the formula:
    // idx(ks,nt) = l16*64 + (((ks*4+quad)^l16sw)*8) + nt*1024
    int kidx0 = l16 * 64 + (((0 * 4 + quad) ^ l16sw) * 8);
    int kidx1 = l16 * 64 + (((1 * 4 + quad) ^ l16sw) * 8);
    // PT write base: l16*64 + (((ntl*2+(quad>>1))^l16sw)*8) + (quad&1)*4
    int pw0 = l16 * 64 + (((0 + (quad >> 1)) ^ l16sw) * 8) + (quad & 1) * 4;  // ntl=0
    int pw1 = l16 * 64 + (((2 + (quad >> 1)) ^ l16sw) * 8) + (quad & 1) * 4;  // ntl=1
    int pw2 = l16 * 64 + (((4 + (quad >> 1)) ^ l16sw) * 8) + (quad & 1) * 4;  // ntl=2
    int pw3 = l16 * 64 + (((6 + (quad >> 1)) ^ l16sw) * 8) + (quad & 1) * 4;  // ntl=3

    stage_kv(kg, vg, kl0, vl0, 0);

    auto tilebody = [&](int kt, int cur) {
        __syncthreads();
        if (kt + 1 < 16)
            stage_kv(kg, vg, cur ? kl0 : kl1, cur ? vl0 : vl1, kt + 1);

        // ---- QK^T: kf reused for both q-groups ----
        floatx4 s[4][2];
        for (int nt = 0; nt < 4; nt++)
            for (int g = 0; g < 2; g++) s[nt][g] = (floatx4){0.f, 0.f, 0.f, 0.f};
        __builtin_amdgcn_s_setprio(1);
        for (int ks = 0; ks < 2; ks++) {
            int kb = ks ? kidx1 : kidx0;
            for (int nt = 0; nt < 4; nt++) {
                half8 kf = *(const half8*)&Kt[cur][kb + nt * 1024];
                s[nt][0] = __builtin_amdgcn_mfma_f32_16x16x32_f16(kf, qf[0][ks], s[nt][0], 0, 0, 0);
                s[nt][1] = __builtin_amdgcn_mfma_f32_16x16x32_f16(kf, qf[1][ks], s[nt][1], 0, 0, 0);
            }
        }
        __builtin_amdgcn_s_setprio(0);

        // ---- exp-first softmax, both groups interleaved ----
        float ax0 = fmaxf(fmaxf(s[0][0][0], s[0][0][1]), fmaxf(s[0][0][2], s[0][0][3]));
        float ax1 = fmaxf(fmaxf(s[1][0][0], s[1][0][1]), fmaxf(s[1][0][2], s[1][0][3]));
        float ax2 = fmaxf(fmaxf(s[2][0][0], s[2][0][1]), fmaxf(s[2][0][2], s[2][0][3]));
        float ax3 = fmaxf(fmaxf(s[3][0][0], s[3][0][1]), fmaxf(s[3][0][2], s[3][0][3]));
        float bx0 = fmaxf(fmaxf(s[0][1][0], s[0][1][1]), fmaxf(s[0][1][2], s[0][1][3]));
        float bx1 = fmaxf(fmaxf(s[1][1][0], s[1][1][1]), fmaxf(s[1][1][2], s[1][1][3]));
        float bx2 = fmaxf(fmaxf(s[2][1][0], s[2][1][1]), fmaxf(s[2][1][2], s[2][1][3]));
        float bx3 = fmaxf(fmaxf(s[3][1][0], s[3][1][1]), fmaxf(s[3][1][2], s[3][1][3]));
        float mx0 = fmaxf(fmaxf(ax0, ax1), fmaxf(ax2, ax3));
        float mx1 = fmaxf(fmaxf(bx0, bx1), fmaxf(bx2, bx3));

        for (int nt = 0; nt < 4; nt++)
            for (int r = 0; r < 4; r++) {
                s[nt][0][r] = EXP2F(s[nt][0][r] - m0);
                s[nt][1][r] = EXP2F(s[nt][1][r] - m1);
            }
        float ra0 = (s[0][0][0] + s[0][0][1]) + (s[0][0][2] + s[0][0][3]);
        float ra1 = (s[1][0][0] + s[1][0][1]) + (s[1][0][2] + s[1][0][3]);
        float ra2 = (s[2][0][0] + s[2][0][1]) + (s[2][0][2] + s[2][0][3]);
        float ra3 = (s[3][0][0] + s[3][0][1]) + (s[3][0][2] + s[3][0][3]);
        float rb0 = (s[0][1][0] + s[0][1][1]) + (s[0][1][2] + s[0][1][3]);
        float rb1 = (s[1][1][0] + s[1][1][1]) + (s[1][1][2] + s[1][1][3]);
        float rb2 = (s[2][1][0] + s[2][1][1]) + (s[2][1][2] + s[2][1][3]);
        float rb3 = (s[3][1][0] + s[3][1][1]) + (s[3][1][2] + s[3][1][3]);
        float rs0 = (ra0 + ra1) + (ra2 + ra3);
        float rs1 = (rb0 + rb1) + (rb2 + rb3);

        float t0 = __shfl_xor(mx0, 16, 64);
        float t1 = __shfl_xor(mx1, 16, 64);
        float t2 = __shfl_xor(rs0, 16, 64);
        float t3 = __shfl_xor(rs1, 16, 64);
        mx0 = fmaxf(mx0, t0); mx1 = fmaxf(mx1, t1); rs0 += t2; rs1 += t3;
        t0 = __shfl_xor(mx0, 32, 64);
        t1 = __shfl_xor(mx1, 32, 64);
        t2 = __shfl_xor(rs0, 32, 64);
        t3 = __shfl_xor(rs1, 32, 64);
        mx0 = fmaxf(mx0, t0); mx1 = fmaxf(mx1, t1); rs0 += t2; rs1 += t3;

        if (__any(fmaxf(mx0 - m0, mx1 - m1) > 11.5443f)) {
            float mn0 = fmaxf(m0, mx0), mn1 = fmaxf(m1, mx1);
            float al0 = EXP2F(m0 - mn0), al1 = EXP2F(m1 - mn1);
            m0 = mn0; m1 = mn1;
            l0 *= al0; l1 *= al1;
            rs0 *= al0; rs1 *= al1;
            for (int nt = 0; nt < 4; nt++)
                for (int r = 0; r < 4; r++) {
                    s[nt][0][r] *= al0; o[nt][0][r] *= al0;
                    s[nt][1][r] *= al1; o[nt][1][r] *= al1;
                }
        }
        l0 += rs0; l1 += rs1;

        // ---- pack P^T (cvt_pkrtz: 2 ops per half4v; __fp16->_Float16 casts are no-ops) ----
        for (int g = 0; g < 2; g++) {
            int pw[4] = {pw0, pw1, pw2, pw3};
            for (int ntl = 0; ntl < 4; ntl++) {
                fp16x2 lo = __builtin_amdgcn_cvt_pkrtz(s[ntl][g][0], s[ntl][g][1]);
                fp16x2 hi = __builtin_amdgcn_cvt_pkrtz(s[ntl][g][2], s[ntl][g][3]);
                half4v p4;
                p4[0] = (_Float16)lo[0]; p4[1] = (_Float16)lo[1];
                p4[2] = (_Float16)hi[0]; p4[3] = (_Float16)hi[1];
                *(half4v*)&PT[wave][g][pw[ntl]] = p4;
            }
        }

        // ---- PV: vf reused for both q-groups ----
        __builtin_amdgcn_s_setprio(1);
        for (int ks2 = 0; ks2 < 2; ks2++) {
            int kb = ks2 ? kidx1 : kidx0;
            half8 pf0 = *(const half8*)&PT[wave][0][kb];
            half8 pf1 = *(const half8*)&PT[wave][1][kb];
            for (int nt = 0; nt < 4; nt++) {
                half8 vf = *(const half8*)&Vt[cur][kb + nt * 1024];
                o[nt][0] = __builtin_amdgcn_mfma_f32_16x16x32_f16(vf, pf0, o[nt][0], 0, 0, 0);
                o[nt][1] = __builtin_amdgcn_mfma_f32_16x16x32_f16(vf, pf1, o[nt][1], 0, 0, 0);
            }
        }
        __builtin_amdgcn_s_setprio(0);
    };

    for (int kt2 = 0; kt2 < 8; kt2++) {
        tilebody(2 * kt2, 0);
        tilebody(2 * kt2 + 1, 1);
    }

    float inv0 = 1.0f / l0, inv1 = 1.0f / l1;
    float* outb = out + ((size_t)b * NN) * DD + h * DHH;
    for (int g = 0; g < 2; g++) {
        int row = qt * 128 + wave * 32 + g * 16 + l16;
        float inv = g ? inv1 : inv0;
        for (int nt = 0; nt < 4; nt++) {
            float4 st;
            st.x = o[nt][g][0] * inv; st.y = o[nt][g][1] * inv;
            st.z = o[nt][g][2] * inv; st.w = o[nt][g][3] * inv;
            *(float4*)&outb[(size_t)row * DD + nt * 16 + quad * 4] = st;
        }
    }
}

extern "C" void kernel_launch(void* const* d_in, const int* in_sizes, int n_in,
                              void* d_out, int out_size, void* d_ws, size_t ws_size,
                              hipStream_t stream) {
    const float* x  = (const float*)d_in[0];
    const float* Wq = (const float*)d_in[1];
    const float* bq = (const float*)d_in[2];
    const float* Wk = (const float*)d_in[3];
    const float* bk = (const float*)d_in[4];
    const float* Wv = (const float*)d_in[5];
    const float* bv = (const float*)d_in[6];
    float* out = (float*)d_out;

    _Float16* Wt  = (_Float16*)d_ws;
    _Float16* QKV = Wt + (size_t)3 * DD * DD;

    hipLaunchKernelGGL(cvt_kernel, dim3(192), dim3(256), 0, stream,
                       Wq, Wk, Wv, Wt);
    hipLaunchKernelGGL(qkv_gemm_kernel, dim3(64, 4, 3), dim3(256), 0, stream,
                       x, Wt, bq, bk, bv, QKV);
    hipLaunchKernelGGL(attn_kernel, dim3(512), dim3(256), 0, stream, QKV, out);
}